// Round 4
// baseline (386.869 us; speedup 1.0000x reference)
//
#include <hip/hip_runtime.h>
#include <math.h>

// Volume dims (fixed by the problem: IMG_SHAPE = (256,256,256))
#define DD 256
#define HH 256
#define WW 256
#define G     4   // voxels per pipeline group
#define NITER 8   // groups per thread -> 32 voxels per thread along i

// float2 with 4-byte alignment: lets us load a k-adjacent corner PAIR with a
// single global_load_dwordx2 at any dword-aligned address (gfx950 supports
// unaligned multi-dword global loads).
typedef float f2v __attribute__((ext_vector_type(2)));
typedef f2v __attribute__((aligned(4))) f2u;

// ---------------------------------------------------------------------------
// Kernel 1: one thread computes the 3x4 resampling transform
// T = rows 0..2 of inv(flo_v2r) @ T_rig @ ref_v2r -> 12 floats in d_ws.
// ---------------------------------------------------------------------------
__global__ void compute_T_kernel(const float* __restrict__ angle,
                                 const float* __restrict__ trans,
                                 const float* __restrict__ ref_v2r,
                                 const float* __restrict__ flo_v2r,
                                 const float* __restrict__ cog,
                                 float* __restrict__ Tout /* 12 floats */) {
    if (blockIdx.x != 0 || threadIdx.x != 0) return;

    const float ax = angle[0], ay = angle[1], az = angle[2];
    const float cx = cosf(ax), sx = sinf(ax);
    const float cy = cosf(ay), sy = sinf(ay);
    const float cz = cosf(az), sz = sinf(az);

    // R = Rx @ Ry @ Rz ;  Rx@Ry = [[cy,0,sy],[sx*sy,cx,-sx*cy],[-cx*sy,sx,cx*cy]]
    float R[3][3];
    const float a00 = cy,       a01 = 0.0f, a02 = sy;
    const float a10 = sx * sy,  a11 = cx,   a12 = -sx * cy;
    const float a20 = -cx * sy, a21 = sx,   a22 = cx * cy;
    R[0][0] = a00 * cz + a01 * sz; R[0][1] = -a00 * sz + a01 * cz; R[0][2] = a02;
    R[1][0] = a10 * cz + a11 * sz; R[1][1] = -a10 * sz + a11 * cz; R[1][2] = a12;
    R[2][0] = a20 * cz + a21 * sz; R[2][1] = -a20 * sz + a21 * cz; R[2][2] = a22;

    // T_rig: linear part R, translation cog + t - R@cog
    float Trig[4][4];
    for (int r = 0; r < 4; ++r)
        for (int c = 0; c < 4; ++c)
            Trig[r][c] = (r == c) ? 1.0f : 0.0f;
    for (int r = 0; r < 3; ++r) {
        for (int c = 0; c < 3; ++c) Trig[r][c] = R[r][c];
        Trig[r][3] = cog[r] + trans[r]
                   - (R[r][0] * cog[0] + R[r][1] * cog[1] + R[r][2] * cog[2]);
    }

    // Closed-form 4x4 inverse of flo_v2r (adjugate).
    float m[16], inv[16];
    for (int q = 0; q < 16; ++q) m[q] = flo_v2r[q];
    inv[0]  =  m[5]*m[10]*m[15] - m[5]*m[11]*m[14] - m[9]*m[6]*m[15]
             + m[9]*m[7]*m[14] + m[13]*m[6]*m[11] - m[13]*m[7]*m[10];
    inv[4]  = -m[4]*m[10]*m[15] + m[4]*m[11]*m[14] + m[8]*m[6]*m[15]
             - m[8]*m[7]*m[14] - m[12]*m[6]*m[11] + m[12]*m[7]*m[10];
    inv[8]  =  m[4]*m[9]*m[15] - m[4]*m[11]*m[13] - m[8]*m[5]*m[15]
             + m[8]*m[7]*m[13] + m[12]*m[5]*m[11] - m[12]*m[7]*m[9];
    inv[12] = -m[4]*m[9]*m[14] + m[4]*m[10]*m[13] + m[8]*m[5]*m[14]
             - m[8]*m[6]*m[13] - m[12]*m[5]*m[10] + m[12]*m[6]*m[9];
    inv[1]  = -m[1]*m[10]*m[15] + m[1]*m[11]*m[14] + m[9]*m[2]*m[15]
             - m[9]*m[3]*m[14] - m[13]*m[2]*m[11] + m[13]*m[3]*m[10];
    inv[5]  =  m[0]*m[10]*m[15] - m[0]*m[11]*m[14] - m[8]*m[2]*m[15]
             + m[8]*m[3]*m[14] + m[12]*m[2]*m[11] - m[12]*m[3]*m[10];
    inv[9]  = -m[0]*m[9]*m[15] + m[0]*m[11]*m[13] + m[8]*m[1]*m[15]
             - m[8]*m[3]*m[13] - m[12]*m[1]*m[11] + m[12]*m[3]*m[9];
    inv[13] =  m[0]*m[9]*m[14] - m[0]*m[10]*m[13] - m[8]*m[1]*m[14]
             + m[8]*m[2]*m[13] + m[12]*m[1]*m[10] - m[12]*m[2]*m[9];
    inv[2]  =  m[1]*m[6]*m[15] - m[1]*m[7]*m[14] - m[5]*m[2]*m[15]
             + m[5]*m[3]*m[14] + m[13]*m[2]*m[7] - m[13]*m[3]*m[6];
    inv[6]  = -m[0]*m[6]*m[15] + m[0]*m[7]*m[14] + m[4]*m[2]*m[15]
             - m[4]*m[3]*m[14] - m[12]*m[2]*m[7] + m[12]*m[3]*m[6];
    inv[10] =  m[0]*m[5]*m[15] - m[0]*m[7]*m[13] - m[4]*m[1]*m[15]
             + m[4]*m[3]*m[13] + m[12]*m[1]*m[7] - m[12]*m[3]*m[5];
    inv[14] = -m[0]*m[5]*m[14] + m[0]*m[6]*m[13] + m[4]*m[1]*m[14]
             - m[4]*m[2]*m[13] - m[12]*m[1]*m[6] + m[12]*m[2]*m[5];
    inv[3]  = -m[1]*m[6]*m[11] + m[1]*m[7]*m[10] + m[5]*m[2]*m[11]
             - m[5]*m[3]*m[10] - m[9]*m[2]*m[7] + m[9]*m[3]*m[6];
    inv[7]  =  m[0]*m[6]*m[11] - m[0]*m[7]*m[10] - m[4]*m[2]*m[11]
             + m[4]*m[3]*m[10] + m[8]*m[2]*m[7] - m[8]*m[3]*m[6];
    inv[11] = -m[0]*m[5]*m[11] + m[0]*m[7]*m[9] + m[4]*m[1]*m[11]
             - m[4]*m[3]*m[9] - m[8]*m[1]*m[7] + m[8]*m[3]*m[5];
    inv[15] =  m[0]*m[5]*m[10] - m[0]*m[6]*m[9] - m[4]*m[1]*m[10]
             + m[4]*m[2]*m[9] + m[8]*m[1]*m[6] - m[8]*m[2]*m[5];
    const float det = m[0]*inv[0] + m[1]*inv[4] + m[2]*inv[8] + m[3]*inv[12];
    const float rdet = 1.0f / det;

    // M1 = Trig @ ref_v2r ; T = invF @ M1 ; rows 0..2 out
    float M1[4][4];
    for (int r = 0; r < 4; ++r)
        for (int c = 0; c < 4; ++c) {
            float s = 0.0f;
            for (int q = 0; q < 4; ++q) s += Trig[r][q] * ref_v2r[q * 4 + c];
            M1[r][c] = s;
        }
    for (int r = 0; r < 3; ++r)
        for (int c = 0; c < 4; ++c) {
            float s = 0.0f;
            for (int q = 0; q < 4; ++q) s += (inv[r * 4 + q] * rdet) * M1[q][c];
            Tout[r * 4 + c] = s;
        }
}

// ---------------------------------------------------------------------------
// Kernel 2: trilinear warp, SOFTWARE-PIPELINED double-buffered gather loop.
//
// History:
// R5: gather-latency bound (all pipes idle, VGPR=36, ~8 loads in flight).
// R6: two-phase source structure re-fused by compiler (VGPR=40, no change).
// R7: asm-pin+sched_barrier stuck (VGPR=80, 32 loads in flight) 109->88us,
//     but crossed the 64-VGPR occupancy cliff (8->4 waves/SIMD, occ 23%).
// R8: IPT=4 + launch_bounds(256,8): 64-reg budget too small, payload went
//     through AGPRs (VGPR=32 reported), occ 60% but dur 100us. WORSE.
// R7/R8 shared flaw: single-shot issue->wait->consume, wave dies; one full
//     ~500cy latency exposure per wave vs ~400cy useful work => <50% eff.
// R9: depth-1 software pipeline (ISSUE(g+1) -> PIN(g) -> CONSUME(g)) but
//     FAILED NUMERICS (absmax 0.379): group anchor via fmaf(IT*G, t0, di0)
//     changed coordinate rounding ~3e-5 -> a few voxels flipped across the
//     ok-mask boundary (output jumps to 0 there; O(1) error).
// R10 (this version): same pipeline, bit-exact R8 numerics. Each group's
//     anchor uses the IDENTICAL expression R8 used per-thread:
//     t0*(float)(i0+IT*G) + t1*gj + t2*gk + t3  (i multiple of 4), then <=3
//     sequential adds — every coordinate bit-matches the passing R8 kernel.
//     launch_bounds(256,4): VGPR cap 128, expect ~110 => 4 waves/SIMD.
//     Grid 2048 blocks, XCD brick map kept.
// ---------------------------------------------------------------------------
__global__ __launch_bounds__(256, 4) void warp_kernel(
        const float* __restrict__ vol,
        const float* __restrict__ T,
        float* __restrict__ out) {
    // Wave-uniform scalar loads of the transform.
    const float t0 = T[0],  t1 = T[1],  t2  = T[2],  t3  = T[3];
    const float t4 = T[4],  t5 = T[5],  t6  = T[6],  t7  = T[7];
    const float t8 = T[8],  t9 = T[9],  t10 = T[10], t11 = T[11];

    // Brick mapping: xcd -> 2x2x2 brick of 128^3 (R3: FETCH 232->36 MB).
    // Per brick: 4 i-tiles(32) x 32 j-tiles(4) x 2 k-tiles(64) = 256 blocks.
    const int bid = blockIdx.x;
    const int xcd = bid & 7;
    const int n = bid >> 3;          // 0..255 per brick
    const int bi = (xcd >> 2) & 1;
    const int bj = (xcd >> 1) & 1;
    const int bk = xcd & 1;
    const int kt = n & 1;            // 2 k-tiles of 64
    const int jt = (n >> 1) & 31;    // 32 j-tiles of 4
    const int it2 = n >> 6;          // 4 i-tiles of 32

    const int tx = threadIdx.x & 63; // k within tile (wave = contiguous k)
    const int ty = threadIdx.x >> 6; // j within tile

    const int i0 = (bi << 7) + (it2 << 5);
    const int j  = (bj << 7) + (jt << 2) + ty;
    const int k  = (bk << 7) + (kt << 6) + tx;

    const float gj = (float)j, gk = (float)k;
    const int out_base = (i0 << 16) + (j << 8) + k;

    // Per-group state: 16 corner-pair loads (32 VGPR), 12 weights, 1 mask.
    f2v vA[G][4], vB[G][4];
    float wA[G][3], wB[G][3];
    unsigned int mA, mB;

// Issue one group: addr calc, weights, bounds mask, 16 dwordx2 loads.
// Anchor per group uses the EXACT expression the passing R8 kernel used
// per-thread (i multiple of 4), then <=3 sequential adds -> coordinates are
// bit-identical to R8 for every voxel.  (R9's fmaf re-anchor perturbed
// rounding ~3e-5 and flipped ok-mask voxels: absmax 0.38.)
#define ISSUE(V, W, M, IT) do {                                              \
    const float gi_ = (float)(i0 + (IT) * G);                                \
    float di_ = t0 * gi_ + t1 * gj + t2  * gk + t3;                          \
    float dj_ = t4 * gi_ + t5 * gj + t6  * gk + t7;                          \
    float dk_ = t8 * gi_ + t9 * gj + t10 * gk + t11;                         \
    M = 0u;                                                                  \
    _Pragma("unroll")                                                        \
    for (int s_ = 0; s_ < G; ++s_) {                                         \
        const float cdi = fminf(fmaxf(di_, 0.0f), (float)(DD - 1));          \
        const float cdj = fminf(fmaxf(dj_, 0.0f), (float)(HH - 1));          \
        const float cdk = fminf(fmaxf(dk_, 0.0f), (float)(WW - 1));          \
        const int fi = (int)cdi;                                             \
        const int fj = (int)cdj;                                             \
        const int fk = (int)cdk;                                             \
        const int ci = min(fi + 1, DD - 1);                                  \
        const int cj = min(fj + 1, HH - 1);                                  \
        const int pk = min(fk, WW - 2);   /* pair base: [pk, pk+1] */        \
        /* wk relative to pair base: fk==255 -> pk=254, wk=1.0 -> pair.y */  \
        W[s_][0] = cdi - (float)fi;                                          \
        W[s_][1] = cdj - (float)fj;                                          \
        W[s_][2] = cdk - (float)pk;                                          \
        const bool ok_ = (di_ >= 0.0f) & (di_ <= (float)(DD - 1)) &          \
                         (dj_ >= 0.0f) & (dj_ <= (float)(HH - 1)) &          \
                         (dk_ >= 0.0f) & (dk_ <= (float)(WW - 1));           \
        M |= (ok_ ? 1u : 0u) << s_;                                          \
        const int fi_o = fi << 16, ci_o = ci << 16;                          \
        const int fj_o = fj << 8,  cj_o = cj << 8;                           \
        V[s_][0] = *(const f2u*)(vol + (fi_o + fj_o + pk));                  \
        V[s_][1] = *(const f2u*)(vol + (fi_o + cj_o + pk));                  \
        V[s_][2] = *(const f2u*)(vol + (ci_o + fj_o + pk));                  \
        V[s_][3] = *(const f2u*)(vol + (ci_o + cj_o + pk));                  \
        di_ += t0; dj_ += t4; dk_ += t8;                                     \
    }                                                                        \
} while (0)

// Pin the group's payload (forces the waitcnt here, after the NEXT group's
// loads are already issued) and fence the scheduler on both sides.
#define PIN(V) do {                                                          \
    __builtin_amdgcn_sched_barrier(0);                                       \
    _Pragma("unroll")                                                        \
    for (int s_ = 0; s_ < G; ++s_) {                                         \
        _Pragma("unroll")                                                    \
        for (int c_ = 0; c_ < 4; ++c_) asm volatile("" : "+v"(V[s_][c_]));   \
    }                                                                        \
    __builtin_amdgcn_sched_barrier(0);                                       \
} while (0)

// Consume one group: pure lerp + masked store (no coord recompute).
#define CONSUME(V, W, M, IT) do {                                            \
    _Pragma("unroll")                                                        \
    for (int s_ = 0; s_ < G; ++s_) {                                         \
        const float wi = W[s_][0], wj = W[s_][1], wk = W[s_][2];             \
        const float c00 = V[s_][0].x + (V[s_][0].y - V[s_][0].x) * wk;       \
        const float c01 = V[s_][1].x + (V[s_][1].y - V[s_][1].x) * wk;       \
        const float c10 = V[s_][2].x + (V[s_][2].y - V[s_][2].x) * wk;       \
        const float c11 = V[s_][3].x + (V[s_][3].y - V[s_][3].x) * wk;       \
        const float c0  = c00 + (c01 - c00) * wj;                            \
        const float c1  = c10 + (c11 - c10) * wj;                            \
        const float val = c0 + (c1 - c0) * wi;                               \
        const bool ok_ = (M >> s_) & 1u;                                     \
        __builtin_nontemporal_store(ok_ ? val : 0.0f,                        \
            &out[out_base + ((((IT) * G) + s_) << 16)]);                     \
    }                                                                        \
} while (0)

    // Prologue: fill buffer A.
    ISSUE(vA, wA, mA, 0);

    // Steady state: issue next, then wait-consume current.
#pragma unroll
    for (int ot = 0; ot < NITER / 2; ++ot) {
        ISSUE(vB, wB, mB, 2 * ot + 1);
        PIN(vA);
        CONSUME(vA, wA, mA, 2 * ot);
        if (2 * ot + 2 < NITER) ISSUE(vA, wA, mA, 2 * ot + 2);
        PIN(vB);
        CONSUME(vB, wB, mB, 2 * ot + 1);
    }

#undef ISSUE
#undef PIN
#undef CONSUME
}

extern "C" void kernel_launch(void* const* d_in, const int* in_sizes, int n_in,
                              void* d_out, int out_size, void* d_ws, size_t ws_size,
                              hipStream_t stream) {
    const float* image_targ  = (const float*)d_in[0];
    const float* angle       = (const float*)d_in[1];
    const float* translation = (const float*)d_in[2];
    const float* ref_v2r     = (const float*)d_in[3];
    const float* flo_v2r     = (const float*)d_in[4];
    const float* cog         = (const float*)d_in[5];
    float* out = (float*)d_out;
    float* Tws = (float*)d_ws;   // 12 floats

    compute_T_kernel<<<1, 64, 0, stream>>>(angle, translation, ref_v2r,
                                           flo_v2r, cog, Tws);
    // 2048 blocks: 8 bricks x (4 i-tiles x 32 j-tiles x 2 k-tiles).
    warp_kernel<<<(DD * HH * WW) / (256 * G * NITER), 256, 0, stream>>>(
        image_targ, Tws, out);
}

// Round 5
// 189.221 us; speedup vs baseline: 2.0445x; 2.0445x over previous
//
#include <hip/hip_runtime.h>
#include <math.h>

// Volume dims (fixed by the problem: IMG_SHAPE = (256,256,256))
#define DD 256
#define HH 256
#define WW 256
#define G     4   // voxels per pipeline group
#define NITER 8   // groups per thread -> 32 voxels per thread along i

// float2 with 4-byte alignment: lets us load a k-adjacent corner PAIR with a
// single global_load_dwordx2 at any dword-aligned address (gfx950 supports
// unaligned multi-dword global loads).
typedef float f2v __attribute__((ext_vector_type(2)));
typedef f2v __attribute__((aligned(4))) f2u;

// ---------------------------------------------------------------------------
// Kernel 1: one thread computes the 3x4 resampling transform
// T = rows 0..2 of inv(flo_v2r) @ T_rig @ ref_v2r -> 12 floats in d_ws.
// ---------------------------------------------------------------------------
__global__ void compute_T_kernel(const float* __restrict__ angle,
                                 const float* __restrict__ trans,
                                 const float* __restrict__ ref_v2r,
                                 const float* __restrict__ flo_v2r,
                                 const float* __restrict__ cog,
                                 float* __restrict__ Tout /* 12 floats */) {
    if (blockIdx.x != 0 || threadIdx.x != 0) return;

    const float ax = angle[0], ay = angle[1], az = angle[2];
    const float cx = cosf(ax), sx = sinf(ax);
    const float cy = cosf(ay), sy = sinf(ay);
    const float cz = cosf(az), sz = sinf(az);

    // R = Rx @ Ry @ Rz ;  Rx@Ry = [[cy,0,sy],[sx*sy,cx,-sx*cy],[-cx*sy,sx,cx*cy]]
    float R[3][3];
    const float a00 = cy,       a01 = 0.0f, a02 = sy;
    const float a10 = sx * sy,  a11 = cx,   a12 = -sx * cy;
    const float a20 = -cx * sy, a21 = sx,   a22 = cx * cy;
    R[0][0] = a00 * cz + a01 * sz; R[0][1] = -a00 * sz + a01 * cz; R[0][2] = a02;
    R[1][0] = a10 * cz + a11 * sz; R[1][1] = -a10 * sz + a11 * cz; R[1][2] = a12;
    R[2][0] = a20 * cz + a21 * sz; R[2][1] = -a20 * sz + a21 * cz; R[2][2] = a22;

    // T_rig: linear part R, translation cog + t - R@cog
    float Trig[4][4];
    for (int r = 0; r < 4; ++r)
        for (int c = 0; c < 4; ++c)
            Trig[r][c] = (r == c) ? 1.0f : 0.0f;
    for (int r = 0; r < 3; ++r) {
        for (int c = 0; c < 3; ++c) Trig[r][c] = R[r][c];
        Trig[r][3] = cog[r] + trans[r]
                   - (R[r][0] * cog[0] + R[r][1] * cog[1] + R[r][2] * cog[2]);
    }

    // Closed-form 4x4 inverse of flo_v2r (adjugate).
    float m[16], inv[16];
    for (int q = 0; q < 16; ++q) m[q] = flo_v2r[q];
    inv[0]  =  m[5]*m[10]*m[15] - m[5]*m[11]*m[14] - m[9]*m[6]*m[15]
             + m[9]*m[7]*m[14] + m[13]*m[6]*m[11] - m[13]*m[7]*m[10];
    inv[4]  = -m[4]*m[10]*m[15] + m[4]*m[11]*m[14] + m[8]*m[6]*m[15]
             - m[8]*m[7]*m[14] - m[12]*m[6]*m[11] + m[12]*m[7]*m[10];
    inv[8]  =  m[4]*m[9]*m[15] - m[4]*m[11]*m[13] - m[8]*m[5]*m[15]
             + m[8]*m[7]*m[13] + m[12]*m[5]*m[11] - m[12]*m[7]*m[9];
    inv[12] = -m[4]*m[9]*m[14] + m[4]*m[10]*m[13] + m[8]*m[5]*m[14]
             - m[8]*m[6]*m[13] - m[12]*m[5]*m[10] + m[12]*m[6]*m[9];
    inv[1]  = -m[1]*m[10]*m[15] + m[1]*m[11]*m[14] + m[9]*m[2]*m[15]
             - m[9]*m[3]*m[14] - m[13]*m[2]*m[11] + m[13]*m[3]*m[10];
    inv[5]  =  m[0]*m[10]*m[15] - m[0]*m[11]*m[14] - m[8]*m[2]*m[15]
             + m[8]*m[3]*m[14] + m[12]*m[2]*m[11] - m[12]*m[3]*m[10];
    inv[9]  = -m[0]*m[9]*m[15] + m[0]*m[11]*m[13] + m[8]*m[1]*m[15]
             - m[8]*m[3]*m[13] - m[12]*m[1]*m[11] + m[12]*m[3]*m[9];
    inv[13] =  m[0]*m[9]*m[14] - m[0]*m[10]*m[13] - m[8]*m[1]*m[14]
             + m[8]*m[2]*m[13] + m[12]*m[1]*m[10] - m[12]*m[2]*m[9];
    inv[2]  =  m[1]*m[6]*m[15] - m[1]*m[7]*m[14] - m[5]*m[2]*m[15]
             + m[5]*m[3]*m[14] + m[13]*m[2]*m[7] - m[13]*m[3]*m[6];
    inv[6]  = -m[0]*m[6]*m[15] + m[0]*m[7]*m[14] + m[4]*m[2]*m[15]
             - m[4]*m[3]*m[14] - m[12]*m[2]*m[7] + m[12]*m[3]*m[6];
    inv[10] =  m[0]*m[5]*m[15] - m[0]*m[7]*m[13] - m[4]*m[1]*m[15]
             + m[4]*m[3]*m[13] + m[12]*m[1]*m[7] - m[12]*m[3]*m[5];
    inv[14] = -m[0]*m[5]*m[14] + m[0]*m[6]*m[13] + m[4]*m[1]*m[14]
             - m[4]*m[2]*m[13] - m[12]*m[1]*m[6] + m[12]*m[2]*m[5];
    inv[3]  = -m[1]*m[6]*m[11] + m[1]*m[7]*m[10] + m[5]*m[2]*m[11]
             - m[5]*m[3]*m[10] - m[9]*m[2]*m[7] + m[9]*m[3]*m[6];
    inv[7]  =  m[0]*m[6]*m[11] - m[0]*m[7]*m[10] - m[4]*m[2]*m[11]
             + m[4]*m[3]*m[10] + m[8]*m[2]*m[7] - m[8]*m[3]*m[6];
    inv[11] = -m[0]*m[5]*m[11] + m[0]*m[7]*m[9] + m[4]*m[1]*m[11]
             - m[4]*m[3]*m[9] - m[8]*m[1]*m[7] + m[8]*m[3]*m[5];
    inv[15] =  m[0]*m[5]*m[10] - m[0]*m[6]*m[9] - m[4]*m[1]*m[10]
             + m[4]*m[2]*m[9] + m[8]*m[1]*m[6] - m[8]*m[2]*m[5];
    const float det = m[0]*inv[0] + m[1]*inv[4] + m[2]*inv[8] + m[3]*inv[12];
    const float rdet = 1.0f / det;

    // M1 = Trig @ ref_v2r ; T = invF @ M1 ; rows 0..2 out
    float M1[4][4];
    for (int r = 0; r < 4; ++r)
        for (int c = 0; c < 4; ++c) {
            float s = 0.0f;
            for (int q = 0; q < 4; ++q) s += Trig[r][q] * ref_v2r[q * 4 + c];
            M1[r][c] = s;
        }
    for (int r = 0; r < 3; ++r)
        for (int c = 0; c < 4; ++c) {
            float s = 0.0f;
            for (int q = 0; q < 4; ++q) s += (inv[r * 4 + q] * rdet) * M1[q][c];
            Tout[r * 4 + c] = s;
        }
}

// ---------------------------------------------------------------------------
// Kernel 2: trilinear warp, SOFTWARE-PIPELINED double-buffered gather loop.
//
// History:
// R5: gather-latency bound (all pipes idle, VGPR=36, ~8 loads in flight).
// R6: two-phase source structure re-fused by compiler (VGPR=40, no change).
// R7: asm-pin+sched_barrier stuck (VGPR=80, 32 loads in flight) 109->88us.
//     NOTE: plain __launch_bounds__(256), allocator chose 80 VGPRs cleanly.
// R8: launch_bounds(256,8) (cap 64): payload shoved through AGPRs, 100us.
// R9: depth-1 pipeline, broke numerics (fmaf re-anchor flipped ok-mask
//     voxels, absmax 0.379).
// R10: pipeline + bit-exact R8 numerics -> PASSED, but launch_bounds(256,4)
//     (cap 128) < peak live state (~120 payload+weights+addr temps) =>
//     allocator SPILLED: VGPR=64 reported, FETCH 36->232 MB, WRITE 65->432 MB
//     (368 MB of scratch writes), VALUBusy 8%, 309us. Structure right,
//     register cap killed it.
// R11 (this version): single change from R10 — remove the min-waves clause.
//     Plain __launch_bounds__(256) like R7 (the config that allocated
//     cleanly). Expect VGPR ~110-140, zero scratch (WRITE back to exactly
//     64 MB), counted vmcnt(16) at each PIN (in-order VMEM queue: B's loads
//     issued after A's, so materializing A waits for outstanding<=16).
// ---------------------------------------------------------------------------
__global__ __launch_bounds__(256) void warp_kernel(
        const float* __restrict__ vol,
        const float* __restrict__ T,
        float* __restrict__ out) {
    // Wave-uniform scalar loads of the transform.
    const float t0 = T[0],  t1 = T[1],  t2  = T[2],  t3  = T[3];
    const float t4 = T[4],  t5 = T[5],  t6  = T[6],  t7  = T[7];
    const float t8 = T[8],  t9 = T[9],  t10 = T[10], t11 = T[11];

    // Brick mapping: xcd -> 2x2x2 brick of 128^3 (R3: FETCH 232->36 MB).
    // Per brick: 4 i-tiles(32) x 32 j-tiles(4) x 2 k-tiles(64) = 256 blocks.
    const int bid = blockIdx.x;
    const int xcd = bid & 7;
    const int n = bid >> 3;          // 0..255 per brick
    const int bi = (xcd >> 2) & 1;
    const int bj = (xcd >> 1) & 1;
    const int bk = xcd & 1;
    const int kt = n & 1;            // 2 k-tiles of 64
    const int jt = (n >> 1) & 31;    // 32 j-tiles of 4
    const int it2 = n >> 6;          // 4 i-tiles of 32

    const int tx = threadIdx.x & 63; // k within tile (wave = contiguous k)
    const int ty = threadIdx.x >> 6; // j within tile

    const int i0 = (bi << 7) + (it2 << 5);
    const int j  = (bj << 7) + (jt << 2) + ty;
    const int k  = (bk << 7) + (kt << 6) + tx;

    const float gj = (float)j, gk = (float)k;
    const int out_base = (i0 << 16) + (j << 8) + k;

    // Per-group state: 16 corner-pair loads (32 VGPR), 12 weights, 1 mask.
    f2v vA[G][4], vB[G][4];
    float wA[G][3], wB[G][3];
    unsigned int mA, mB;

// Issue one group: addr calc, weights, bounds mask, 16 dwordx2 loads.
// Anchor per group uses the EXACT expression the passing R8 kernel used
// per-thread (i multiple of 4), then <=3 sequential adds -> coordinates are
// bit-identical to R8 for every voxel.  (R9's fmaf re-anchor perturbed
// rounding ~3e-5 and flipped ok-mask voxels: absmax 0.38.)
#define ISSUE(V, W, M, IT) do {                                              \
    const float gi_ = (float)(i0 + (IT) * G);                                \
    float di_ = t0 * gi_ + t1 * gj + t2  * gk + t3;                          \
    float dj_ = t4 * gi_ + t5 * gj + t6  * gk + t7;                          \
    float dk_ = t8 * gi_ + t9 * gj + t10 * gk + t11;                         \
    M = 0u;                                                                  \
    _Pragma("unroll")                                                        \
    for (int s_ = 0; s_ < G; ++s_) {                                         \
        const float cdi = fminf(fmaxf(di_, 0.0f), (float)(DD - 1));          \
        const float cdj = fminf(fmaxf(dj_, 0.0f), (float)(HH - 1));          \
        const float cdk = fminf(fmaxf(dk_, 0.0f), (float)(WW - 1));          \
        const int fi = (int)cdi;                                             \
        const int fj = (int)cdj;                                             \
        const int fk = (int)cdk;                                             \
        const int ci = min(fi + 1, DD - 1);                                  \
        const int cj = min(fj + 1, HH - 1);                                  \
        const int pk = min(fk, WW - 2);   /* pair base: [pk, pk+1] */        \
        /* wk relative to pair base: fk==255 -> pk=254, wk=1.0 -> pair.y */  \
        W[s_][0] = cdi - (float)fi;                                          \
        W[s_][1] = cdj - (float)fj;                                          \
        W[s_][2] = cdk - (float)pk;                                          \
        const bool ok_ = (di_ >= 0.0f) & (di_ <= (float)(DD - 1)) &          \
                         (dj_ >= 0.0f) & (dj_ <= (float)(HH - 1)) &          \
                         (dk_ >= 0.0f) & (dk_ <= (float)(WW - 1));           \
        M |= (ok_ ? 1u : 0u) << s_;                                          \
        const int fi_o = fi << 16, ci_o = ci << 16;                          \
        const int fj_o = fj << 8,  cj_o = cj << 8;                           \
        V[s_][0] = *(const f2u*)(vol + (fi_o + fj_o + pk));                  \
        V[s_][1] = *(const f2u*)(vol + (fi_o + cj_o + pk));                  \
        V[s_][2] = *(const f2u*)(vol + (ci_o + fj_o + pk));                  \
        V[s_][3] = *(const f2u*)(vol + (ci_o + cj_o + pk));                  \
        di_ += t0; dj_ += t4; dk_ += t8;                                     \
    }                                                                        \
} while (0)

// Pin the group's payload (forces the waitcnt here, after the NEXT group's
// loads are already issued) and fence the scheduler on both sides.
#define PIN(V) do {                                                          \
    __builtin_amdgcn_sched_barrier(0);                                       \
    _Pragma("unroll")                                                        \
    for (int s_ = 0; s_ < G; ++s_) {                                         \
        _Pragma("unroll")                                                    \
        for (int c_ = 0; c_ < 4; ++c_) asm volatile("" : "+v"(V[s_][c_]));   \
    }                                                                        \
    __builtin_amdgcn_sched_barrier(0);                                       \
} while (0)

// Consume one group: pure lerp + masked store (no coord recompute).
#define CONSUME(V, W, M, IT) do {                                            \
    _Pragma("unroll")                                                        \
    for (int s_ = 0; s_ < G; ++s_) {                                         \
        const float wi = W[s_][0], wj = W[s_][1], wk = W[s_][2];             \
        const float c00 = V[s_][0].x + (V[s_][0].y - V[s_][0].x) * wk;       \
        const float c01 = V[s_][1].x + (V[s_][1].y - V[s_][1].x) * wk;       \
        const float c10 = V[s_][2].x + (V[s_][2].y - V[s_][2].x) * wk;       \
        const float c11 = V[s_][3].x + (V[s_][3].y - V[s_][3].x) * wk;       \
        const float c0  = c00 + (c01 - c00) * wj;                            \
        const float c1  = c10 + (c11 - c10) * wj;                            \
        const float val = c0 + (c1 - c0) * wi;                               \
        const bool ok_ = (M >> s_) & 1u;                                     \
        __builtin_nontemporal_store(ok_ ? val : 0.0f,                        \
            &out[out_base + ((((IT) * G) + s_) << 16)]);                     \
    }                                                                        \
} while (0)

    // Prologue: fill buffer A.
    ISSUE(vA, wA, mA, 0);

    // Steady state: issue next, then wait-consume current.
#pragma unroll
    for (int ot = 0; ot < NITER / 2; ++ot) {
        ISSUE(vB, wB, mB, 2 * ot + 1);
        PIN(vA);
        CONSUME(vA, wA, mA, 2 * ot);
        if (2 * ot + 2 < NITER) ISSUE(vA, wA, mA, 2 * ot + 2);
        PIN(vB);
        CONSUME(vB, wB, mB, 2 * ot + 1);
    }

#undef ISSUE
#undef PIN
#undef CONSUME
}

extern "C" void kernel_launch(void* const* d_in, const int* in_sizes, int n_in,
                              void* d_out, int out_size, void* d_ws, size_t ws_size,
                              hipStream_t stream) {
    const float* image_targ  = (const float*)d_in[0];
    const float* angle       = (const float*)d_in[1];
    const float* translation = (const float*)d_in[2];
    const float* ref_v2r     = (const float*)d_in[3];
    const float* flo_v2r     = (const float*)d_in[4];
    const float* cog         = (const float*)d_in[5];
    float* out = (float*)d_out;
    float* Tws = (float*)d_ws;   // 12 floats

    compute_T_kernel<<<1, 64, 0, stream>>>(angle, translation, ref_v2r,
                                           flo_v2r, cog, Tws);
    // 2048 blocks: 8 bricks x (4 i-tiles x 32 j-tiles x 2 k-tiles).
    warp_kernel<<<(DD * HH * WW) / (256 * G * NITER), 256, 0, stream>>>(
        image_targ, Tws, out);
}